// Round 12
// baseline (337.801 us; speedup 1.0000x reference)
//
#include <hip/hip_runtime.h>
#include <hip/hip_bf16.h>
#include <math.h>

#define Hdim 1024
#define Bdim 32
#define Ldim 2048
#define Mtot (Bdim*Ldim)   // 65536

typedef __attribute__((ext_vector_type(8))) short short8v;
typedef __attribute__((ext_vector_type(4))) short short4v;
typedef __attribute__((ext_vector_type(4))) float floatx4;

static __device__ inline short f2bf(float f) {
    union { float f; unsigned u; } x; x.f = f;
    unsigned r = x.u + 0x7FFF + ((x.u >> 16) & 1);   // RNE
    return (short)(r >> 16);
}
static __device__ inline short f2bf_hw(float f) {
    __hip_bfloat16 h = __float2bfloat16(f);
    return *reinterpret_cast<short*>(&h);
}

static __device__ inline float fast_tanh(float x) {
    float t = 2.0f * x;
    t = fminf(fmaxf(t, -30.0f), 30.0f);
    float e = __expf(t);
    return (e - 1.0f) / (e + 1.0f);
}

typedef __attribute__((address_space(1))) const void GVT;
typedef __attribute__((address_space(3))) void LVT;
static __device__ inline void gload_lds16(const void* g, void* l) {
    __builtin_amdgcn_global_load_lds((GVT*)g, (LVT*)l, 16, 0, 0);
}

// ---------------- Kernel 0: W_e (= attn_w[:, H:]) f32 -> compact bf16 [1024][1024] ----------------
__global__ __launch_bounds__(256) void convert_w_kernel(
    const float* __restrict__ attn_w, short* __restrict__ w_bf)
{
    int t = blockIdx.x * 256 + threadIdx.x;
    int o = t >> 7;
    int c = t & 127;
    const float* src = attn_w + (size_t)o * 2 * Hdim + Hdim + c * 8;
    float4 a = *(const float4*)(src);
    float4 b = *(const float4*)(src + 4);
    short8v v;
    v[0]=f2bf(a.x); v[1]=f2bf(a.y); v[2]=f2bf(a.z); v[3]=f2bf(a.w);
    v[4]=f2bf(b.x); v[5]=f2bf(b.y); v[6]=f2bf(b.z); v[7]=f2bf(b.w);
    *(short8v*)(w_bf + (size_t)o * Hdim + c * 8) = v;
}

// ---------------- Kernel 1: q[b][o] = hidden[b]·W_h[o] + bias[o] ----------------
__global__ __launch_bounds__(256) void qproj_kernel(
    const float* __restrict__ hidden, const float* __restrict__ attn_w,
    const float* __restrict__ attn_b, float* __restrict__ qbuf)
{
    int w = blockIdx.x * 4 + (threadIdx.x >> 6);
    int lane = threadIdx.x & 63;
    int o = w >> 5;
    int b = w & 31;
    const float* hrow = hidden + b * Hdim;
    const float* wrow = attn_w + (size_t)o * 2 * Hdim;
    float s = 0.f;
    #pragma unroll
    for (int i = 0; i < 16; i++) s += hrow[lane + i*64] * wrow[lane + i*64];
    s += __shfl_xor(s, 1);  s += __shfl_xor(s, 2);  s += __shfl_xor(s, 4);
    s += __shfl_xor(s, 8);  s += __shfl_xor(s, 16); s += __shfl_xor(s, 32);
    if (lane == 0) qbuf[b * Hdim + o] = s + attn_b[o];
}

// ---------------- Kernel 2: fused-A GEMM, 2-deep A-reg pipeline, counted vmcnt ----
// A: f32 global -> regs (issued 2 iters ahead) -> cvt -> swizzled ds_write (1 iter ahead).
// B: bf16 gload_lds, pre-swizzled source. Zero-conflict swizzle chunk ^= (row>>1)&3.
// Barrier: raw s_barrier with vmcnt(4) (B drained, A(t+2) in flight) + lgkmcnt(0).
#define BM 128
#define BN 128
#define BK 32
#define NKT 32

__global__ __launch_bounds__(256, 4) void scores_kernel(
    const float* __restrict__ enc,      // [Mtot][1024] f32 (L,B,H) m=l*32+b
    const short* __restrict__ w_bf,     // [1024][1024] bf16
    const float* __restrict__ qbuf,     // [B][H]
    const float* __restrict__ vvec,     // [H]
    float* __restrict__ spart)          // [8][Mtot]
{
    __shared__ short As[2][BM * BK];    // 2 x 8 KB
    __shared__ short Bs[2][BN * BK];    // 2 x 8 KB
    __shared__ float sred[BM][2];

    // XCD swizzle: 8 nblk sharers of one A-panel on one XCD. grid 4096 = 8*8*64.
    int hw = blockIdx.x;
    int xcd = hw & 7;
    int i5  = hw >> 3;
    int nblk  = i5 & 7;
    int mtile = xcd * 64 + (i5 >> 3);
    int m0 = mtile * BM;
    int n0 = nblk * BN;

    int tid  = threadIdx.x;
    int w    = tid >> 6;
    int l    = tid & 63;
    int wr = w >> 1, wc = w & 1;
    int r15 = l & 15;
    int kc  = l >> 4;
    int rg  = l >> 4;

    // ---- A staging lane constants: slots cover rows arow, arow+64; chunk acol ----
    int arow = tid >> 2;                // 0..63
    int acol = tid & 3;
    int asw  = (tid >> 3) & 3;          // s(row) = (row>>1)&3 (same for both slots)
    const float* agp = enc + (size_t)(m0 + arow) * Hdim + acol * 8;
    const int awoff0 = arow * BK + ((acol ^ asw) * 8);
    const int awoff1 = (arow + 64) * BK + ((acol ^ asw) * 8);

    // ---- B gload staging: pre-swizzled source ----
    const short* bgp = w_bf + (size_t)(n0 + w*32 + (l >> 2)) * Hdim
                            + (((l & 3) ^ ((l >> 3) & 3)) * 8);
#define STAGE_B(bb, k0) do { \
    gload_lds16(bgp + (k0),                      &Bs[bb][(w*32)      * BK]); \
    gload_lds16(bgp + (k0) + 16*(size_t)Hdim,    &Bs[bb][(w*32 + 16) * BK]); \
} while (0)

    // ---- swizzled fragment reads ----
    int q = (r15 >> 1) & 3;
    int rc = (kc ^ q) * 8;
#define LDA(mi) (*(const short8v*)(&As[cur][(wr*64 + (mi)*16 + r15) * BK + rc]))
#define LDB(ni) (*(const short8v*)(&Bs[cur][(wc*64 + (ni)*16 + r15) * BK + rc]))

    floatx4 acc[4][4];
    #pragma unroll
    for (int i = 0; i < 4; i++)
        #pragma unroll
        for (int j = 0; j < 4; j++) acc[i][j] = (floatx4){0.f, 0.f, 0.f, 0.f};

    // two A-reg sets: tile t lives in set t&1
    float4 A0_[4], A1_[4];

#define LOAD_SET0(k0) do { \
    A0_[0] = *(const float4*)(agp + (k0)); \
    A0_[1] = *(const float4*)(agp + (k0) + 4); \
    A0_[2] = *(const float4*)(agp + (k0) + 64*(size_t)Hdim); \
    A0_[3] = *(const float4*)(agp + (k0) + 64*(size_t)Hdim + 4); \
} while (0)
#define LOAD_SET1(k0) do { \
    A1_[0] = *(const float4*)(agp + (k0)); \
    A1_[1] = *(const float4*)(agp + (k0) + 4); \
    A1_[2] = *(const float4*)(agp + (k0) + 64*(size_t)Hdim); \
    A1_[3] = *(const float4*)(agp + (k0) + 64*(size_t)Hdim + 4); \
} while (0)
#define CVT_WRITE(SET, bb) do { \
    short8v s0, s1; \
    s0[0]=f2bf_hw(SET[0].x); s0[1]=f2bf_hw(SET[0].y); s0[2]=f2bf_hw(SET[0].z); s0[3]=f2bf_hw(SET[0].w); \
    s0[4]=f2bf_hw(SET[1].x); s0[5]=f2bf_hw(SET[1].y); s0[6]=f2bf_hw(SET[1].z); s0[7]=f2bf_hw(SET[1].w); \
    s1[0]=f2bf_hw(SET[2].x); s1[1]=f2bf_hw(SET[2].y); s1[2]=f2bf_hw(SET[2].z); s1[3]=f2bf_hw(SET[2].w); \
    s1[4]=f2bf_hw(SET[3].x); s1[5]=f2bf_hw(SET[3].y); s1[6]=f2bf_hw(SET[3].z); s1[7]=f2bf_hw(SET[3].w); \
    *(short8v*)(&As[bb][awoff0]) = s0; \
    *(short8v*)(&As[bb][awoff1]) = s1; \
} while (0)

    // prologue: tile0 -> buf0 (set0), tile1 loads in flight (set1)
    STAGE_B(0, 0);
    LOAD_SET0(0);
    LOAD_SET1(BK);
    CVT_WRITE(A0_, 0);
    __syncthreads();    // one-time full drain

    #pragma unroll 2
    for (int kt = 0; kt < NKT; kt++) {
        int cur = kt & 1;
        int nxt = cur ^ 1;
        bool haveB = (kt + 1 < NKT);
        bool haveA = (kt + 2 < NKT);

        // issue order matters: B first, then A (FIFO -> vmcnt(4) drains B only)
        if (haveB) STAGE_B(nxt, (kt + 1) * BK);
        if (haveA) { if (kt & 1) LOAD_SET1((kt + 2) * BK); else LOAD_SET0((kt + 2) * BK); }

        short8v af[4], bf[4];
        #pragma unroll
        for (int mi = 0; mi < 4; mi++) af[mi] = LDA(mi);
        #pragma unroll
        for (int ni = 0; ni < 4; ni++) bf[ni] = LDB(ni);
        #pragma unroll
        for (int mi = 0; mi < 4; mi++)
            #pragma unroll
            for (int ni = 0; ni < 4; ni++)
                acc[mi][ni] = __builtin_amdgcn_mfma_f32_16x16x32_bf16(af[mi], bf[ni], acc[mi][ni], 0, 0, 0);

        // write tile kt+1's A (loads issued a full iteration ago -> ~covered)
        if (haveB) { if ((kt + 1) & 1) CVT_WRITE(A1_, nxt); else CVT_WRITE(A0_, nxt); }

        if (haveB) {
            if (haveA) asm volatile("s_waitcnt vmcnt(4)" ::: "memory");  // B(t+1) done, A(t+2) flying
            else       asm volatile("s_waitcnt vmcnt(0)" ::: "memory");
            asm volatile("s_waitcnt lgkmcnt(0)" ::: "memory");           // ds_writes visible
            __builtin_amdgcn_s_barrier();
        }
    }

    // ---- epilogue: tanh(proj + q) * v, reduce over this block's 128 cols ----
    #pragma unroll
    for (int mi = 0; mi < 4; mi++) {
        float rs[4] = {0.f, 0.f, 0.f, 0.f};
        #pragma unroll
        for (int ni = 0; ni < 4; ni++) {
            int o = n0 + wc*64 + ni*16 + r15;
            float vo = vvec[o];
            #pragma unroll
            for (int reg = 0; reg < 4; reg++) {
                int trow = wr*64 + mi*16 + rg*4 + reg;
                int b = trow & 31;
                float p = acc[mi][ni][reg] + qbuf[b * Hdim + o];
                rs[reg] += fast_tanh(p) * vo;
            }
        }
        #pragma unroll
        for (int reg = 0; reg < 4; reg++) {
            float s = rs[reg];
            s += __shfl_xor(s, 1); s += __shfl_xor(s, 2);
            s += __shfl_xor(s, 4); s += __shfl_xor(s, 8);
            if (r15 == 0) {
                int trow = wr*64 + mi*16 + rg*4 + reg;
                sred[trow][wc] = s;
            }
        }
    }
    __syncthreads();
    if (tid < BM)
        spart[(size_t)nblk * Mtot + m0 + tid] = sred[tid][0] + sred[tid][1];
#undef STAGE_B
#undef LDA
#undef LDB
#undef LOAD_SET0
#undef LOAD_SET1
#undef CVT_WRITE
}

// ---------------- Kernel 3: reduce 8 partials + softmax over L (per b) ----------------
__global__ __launch_bounds__(256) void softmax_kernel(
    const float* __restrict__ spart,   // [8][Mtot], m = l*32+b
    float* __restrict__ attn)          // [B][L]
{
    int b = blockIdx.x;
    int t = threadIdx.x;
    __shared__ float rmax[4], rsum[4];
    float sv[8];
    float mx = -1e30f;
    #pragma unroll
    for (int i = 0; i < 8; i++) {
        int l = t + i * 256;
        int m = l * Bdim + b;
        float s = 0.f;
        #pragma unroll
        for (int p = 0; p < 8; p++) s += spart[(size_t)p * Mtot + m];
        sv[i] = s;
        mx = fmaxf(mx, s);
    }
    #pragma unroll
    for (int off = 1; off < 64; off <<= 1) mx = fmaxf(mx, __shfl_xor(mx, off));
    if ((t & 63) == 0) rmax[t >> 6] = mx;
    __syncthreads();
    mx = fmaxf(fmaxf(rmax[0], rmax[1]), fmaxf(rmax[2], rmax[3]));
    float sum = 0.f;
    #pragma unroll
    for (int i = 0; i < 8; i++) { sv[i] = __expf(sv[i] - mx); sum += sv[i]; }
    #pragma unroll
    for (int off = 1; off < 64; off <<= 1) sum += __shfl_xor(sum, off);
    if ((t & 63) == 0) rsum[t >> 6] = sum;
    __syncthreads();
    sum = rsum[0] + rsum[1] + rsum[2] + rsum[3];
    float inv = 1.f / sum;
    #pragma unroll
    for (int i = 0; i < 8; i++)
        attn[(size_t)b * Ldim + t + i * 256] = sv[i] * inv;
}

// ---------------- Kernel 4: context partials over L-chunks (f32 enc) ----------------
__global__ __launch_bounds__(256) void context_part_kernel(
    const float* __restrict__ enc,     // [L*B][H] f32
    const float* __restrict__ attn,    // [B][L]
    float* __restrict__ cpart)         // [64][B][H]
{
    int b = blockIdx.x & 31;
    int c = blockIdx.x >> 5;
    int t = threadIdx.x;
    float4 acc = {0.f, 0.f, 0.f, 0.f};
    int l0 = c * 32;
    for (int i = 0; i < 32; i++) {
        int l = l0 + i;
        float a = attn[(size_t)b * Ldim + l];
        float4 e = *(const float4*)(enc + (size_t)(l * Bdim + b) * Hdim + t * 4);
        acc.x += a * e.x; acc.y += a * e.y; acc.z += a * e.z; acc.w += a * e.w;
    }
    *(float4*)(cpart + ((size_t)c * Bdim + b) * Hdim + t * 4) = acc;
}

// ---------------- Kernel 5: reduce context partials ----------------
__global__ __launch_bounds__(256) void context_reduce_kernel(
    const float* __restrict__ cpart, float* __restrict__ out)
{
    int idx = blockIdx.x * 256 + threadIdx.x;
    float s = 0.f;
    for (int c = 0; c < 64; c++) s += cpart[(size_t)c * (Bdim * Hdim) + idx];
    out[idx] = s;
}

extern "C" void kernel_launch(void* const* d_in, const int* in_sizes, int n_in,
                              void* d_out, int out_size, void* d_ws, size_t ws_size,
                              hipStream_t stream)
{
    const float* hidden = (const float*)d_in[0];
    const float* enc    = (const float*)d_in[1];   // (L,B,H), m = l*32+b
    const float* attn_w = (const float*)d_in[2];
    const float* attn_b = (const float*)d_in[3];
    const float* vvec   = (const float*)d_in[4];
    float* out = (float*)d_out;

    char* ws = (char*)d_ws;
    size_t off = 0;
    short* w_bf   = (short*)(ws + off); off += (size_t)Hdim * Hdim * 2;       // 2.1 MB
    float* qbuf   = (float*)(ws + off); off += (size_t)Bdim * Hdim * 4;       // 0.13 MB
    float* spart  = (float*)(ws + off); off += (size_t)8 * Mtot * 4;          // 2.1 MB
    float* attnp  = (float*)(ws + off); off += (size_t)Mtot * 4;              // 0.26 MB
    float* cpart  = (float*)(ws + off);                                       // 8.4 MB

    convert_w_kernel<<<512, 256, 0, stream>>>(attn_w, w_bf);
    qproj_kernel<<<8192, 256, 0, stream>>>(hidden, attn_w, attn_b, qbuf);
    scores_kernel<<<4096, 256, 0, stream>>>(enc, w_bf, qbuf, vvec, spart);
    softmax_kernel<<<Bdim, 256, 0, stream>>>(spart, attnp);
    context_part_kernel<<<2048, 256, 0, stream>>>(enc, attnp, cpart);
    context_reduce_kernel<<<128, 256, 0, stream>>>(cpart, out);
}

// Round 13
// 330.716 us; speedup vs baseline: 1.0214x; 1.0214x over previous
//
#include <hip/hip_runtime.h>
#include <hip/hip_bf16.h>
#include <math.h>

#define Hdim 1024
#define Bdim 32
#define Ldim 2048
#define Mtot (Bdim*Ldim)   // 65536

typedef __attribute__((ext_vector_type(8))) short short8v;
typedef __attribute__((ext_vector_type(4))) short short4v;
typedef __attribute__((ext_vector_type(4))) float floatx4;

static __device__ inline short f2bf(float f) {
    union { float f; unsigned u; } x; x.f = f;
    unsigned r = x.u + 0x7FFF + ((x.u >> 16) & 1);   // RNE
    return (short)(r >> 16);
}
static __device__ inline short f2bf_hw(float f) {
    __hip_bfloat16 h = __float2bfloat16(f);
    return *reinterpret_cast<short*>(&h);
}

static __device__ inline float fast_tanh(float x) {
    float t = 2.0f * x;
    t = fminf(fmaxf(t, -30.0f), 30.0f);
    float e = __expf(t);
    return (e - 1.0f) / (e + 1.0f);
}

typedef __attribute__((address_space(1))) const void GVT;
typedef __attribute__((address_space(3))) void LVT;
static __device__ inline void gload_lds16(const void* g, void* l) {
    __builtin_amdgcn_global_load_lds((GVT*)g, (LVT*)l, 16, 0, 0);
}

// ---------------- Kernel 0: W_e (= attn_w[:, H:]) f32 -> compact bf16 [1024][1024] ----------------
__global__ __launch_bounds__(256) void convert_w_kernel(
    const float* __restrict__ attn_w, short* __restrict__ w_bf)
{
    int t = blockIdx.x * 256 + threadIdx.x;
    int o = t >> 7;
    int c = t & 127;
    const float* src = attn_w + (size_t)o * 2 * Hdim + Hdim + c * 8;
    float4 a = *(const float4*)(src);
    float4 b = *(const float4*)(src + 4);
    short8v v;
    v[0]=f2bf(a.x); v[1]=f2bf(a.y); v[2]=f2bf(a.z); v[3]=f2bf(a.w);
    v[4]=f2bf(b.x); v[5]=f2bf(b.y); v[6]=f2bf(b.z); v[7]=f2bf(b.w);
    *(short8v*)(w_bf + (size_t)o * Hdim + c * 8) = v;
}

// ---------------- Kernel 1: q[b][o] = hidden[b]·W_h[o] + bias[o] ----------------
__global__ __launch_bounds__(256) void qproj_kernel(
    const float* __restrict__ hidden, const float* __restrict__ attn_w,
    const float* __restrict__ attn_b, float* __restrict__ qbuf)
{
    int w = blockIdx.x * 4 + (threadIdx.x >> 6);
    int lane = threadIdx.x & 63;
    int o = w >> 5;
    int b = w & 31;
    const float* hrow = hidden + b * Hdim;
    const float* wrow = attn_w + (size_t)o * 2 * Hdim;
    float s = 0.f;
    #pragma unroll
    for (int i = 0; i < 16; i++) s += hrow[lane + i*64] * wrow[lane + i*64];
    s += __shfl_xor(s, 1);  s += __shfl_xor(s, 2);  s += __shfl_xor(s, 4);
    s += __shfl_xor(s, 8);  s += __shfl_xor(s, 16); s += __shfl_xor(s, 32);
    if (lane == 0) qbuf[b * Hdim + o] = s + attn_b[o];
}

// ---------------- Kernel 2: GEMM with A staged as f32 via global_load_lds ----
// A: f32 enc -> LDS direct (async DMA, zero VGPR); cvt to bf16 at fragment-read.
// B: bf16 w_bf via gload_lds, pre-swizzled source (r11: 0 conflicts).
// A-swizzle (128B rows, 8 chunks): chunk ^= row&7 (2-way free). No reg staging -> no spill.
#define BM 128
#define BN 128
#define BK 32
#define NKT 32

__global__ __launch_bounds__(256, 3) void scores_kernel(
    const float* __restrict__ enc,      // [Mtot][1024] f32 (L,B,H) m=l*32+b
    const short* __restrict__ w_bf,     // [1024][1024] bf16
    const float* __restrict__ qbuf,     // [B][H]
    const float* __restrict__ vvec,     // [H]
    float* __restrict__ spart)          // [8][Mtot]
{
    __shared__ float As[2][BM * BK];    // 2 x 16 KB (f32)
    __shared__ short Bs[2][BN * BK];    // 2 x  8 KB (bf16)
    __shared__ float sred[BM][2];

    // XCD swizzle: 8 nblk sharers of one A-panel on one XCD. grid 4096 = 8*8*64.
    int hw = blockIdx.x;
    int xcd = hw & 7;
    int i5  = hw >> 3;
    int nblk  = i5 & 7;
    int mtile = xcd * 64 + (i5 >> 3);
    int m0 = mtile * BM;
    int n0 = nblk * BN;

    int tid  = threadIdx.x;
    int w    = tid >> 6;
    int l    = tid & 63;
    int wr = w >> 1, wc = w & 1;
    int r15 = l & 15;
    int kc  = l >> 4;
    int rg  = l >> 4;

    // ---- A staging (f32): wave w covers rows [w*32, w*32+32), 4 issues of 8 rows.
    // lane l -> row (l>>3), LDS chunk (l&7); source chunk = (l&7) ^ ((l>>3)&7)
    const float* agp = enc + (size_t)(m0 + w*32 + (l >> 3)) * Hdim
                           + (((l & 7) ^ ((l >> 3) & 7)) * 4);
#define STAGE_A(bb, k0) do { \
    gload_lds16(agp + (k0),                      &As[bb][(w*32)      * BK]); \
    gload_lds16(agp + (k0) +  8*(size_t)Hdim,    &As[bb][(w*32 +  8) * BK]); \
    gload_lds16(agp + (k0) + 16*(size_t)Hdim,    &As[bb][(w*32 + 16) * BK]); \
    gload_lds16(agp + (k0) + 24*(size_t)Hdim,    &As[bb][(w*32 + 24) * BK]); \
} while (0)

    // ---- B staging (bf16): r11 form, 0 conflicts measured ----
    const short* bgp = w_bf + (size_t)(n0 + w*32 + (l >> 2)) * Hdim
                            + (((l & 3) ^ ((l >> 3) & 3)) * 8);
#define STAGE_B(bb, k0) do { \
    gload_lds16(bgp + (k0),                      &Bs[bb][(w*32)      * BK]); \
    gload_lds16(bgp + (k0) + 16*(size_t)Hdim,    &Bs[bb][(w*32 + 16) * BK]); \
} while (0)

    // ---- fragment reads ----
    // A: row R = wr*64+mi*16+r15; f32 chunks (kc*2)^(R&7), (kc*2+1)^(R&7); cvt -> bf16
    int asw = r15 & 7;
    int ac0 = ((kc * 2)     ^ asw) * 4;
    int ac1 = ((kc * 2 + 1) ^ asw) * 4;
#define LDA(mi, dst) do { \
    int R = (wr*64 + (mi)*16 + r15) * BK; \
    float4 lo = *(const float4*)(&As[cur][R + ac0]); \
    float4 hi = *(const float4*)(&As[cur][R + ac1]); \
    dst[0]=f2bf_hw(lo.x); dst[1]=f2bf_hw(lo.y); dst[2]=f2bf_hw(lo.z); dst[3]=f2bf_hw(lo.w); \
    dst[4]=f2bf_hw(hi.x); dst[5]=f2bf_hw(hi.y); dst[6]=f2bf_hw(hi.z); dst[7]=f2bf_hw(hi.w); \
} while (0)
    // B: bf16 chunk (kc ^ ((r15>>1)&3))
    int rc = (kc ^ ((r15 >> 1) & 3)) * 8;
#define LDB(ni) (*(const short8v*)(&Bs[cur][(wc*64 + (ni)*16 + r15) * BK + rc]))

    floatx4 acc[4][4];
    #pragma unroll
    for (int i = 0; i < 4; i++)
        #pragma unroll
        for (int j = 0; j < 4; j++) acc[i][j] = (floatx4){0.f, 0.f, 0.f, 0.f};

    // prologue
    STAGE_A(0, 0);
    STAGE_B(0, 0);
    __syncthreads();

    #pragma unroll 2
    for (int kt = 0; kt < NKT; kt++) {
        int cur = kt & 1;
        int nxt = cur ^ 1;
        if (kt < NKT - 1) {
            STAGE_A(nxt, (kt + 1) * BK);
            STAGE_B(nxt, (kt + 1) * BK);
        }
        short8v af[4], bf[4];
        #pragma unroll
        for (int mi = 0; mi < 4; mi++) LDA(mi, af[mi]);
        #pragma unroll
        for (int ni = 0; ni < 4; ni++) bf[ni] = LDB(ni);
        #pragma unroll
        for (int mi = 0; mi < 4; mi++)
            #pragma unroll
            for (int ni = 0; ni < 4; ni++)
                acc[mi][ni] = __builtin_amdgcn_mfma_f32_16x16x32_bf16(af[mi], bf[ni], acc[mi][ni], 0, 0, 0);
        __syncthreads();   // drains prefetch + LDS reads done (r6-proven structure)
    }

    // ---- epilogue: tanh(proj + q) * v, reduce over this block's 128 cols ----
    #pragma unroll
    for (int mi = 0; mi < 4; mi++) {
        float rs[4] = {0.f, 0.f, 0.f, 0.f};
        #pragma unroll
        for (int ni = 0; ni < 4; ni++) {
            int o = n0 + wc*64 + ni*16 + r15;
            float vo = vvec[o];
            #pragma unroll
            for (int reg = 0; reg < 4; reg++) {
                int trow = wr*64 + mi*16 + rg*4 + reg;
                int b = trow & 31;
                float p = acc[mi][ni][reg] + qbuf[b * Hdim + o];
                rs[reg] += fast_tanh(p) * vo;
            }
        }
        #pragma unroll
        for (int reg = 0; reg < 4; reg++) {
            float s = rs[reg];
            s += __shfl_xor(s, 1); s += __shfl_xor(s, 2);
            s += __shfl_xor(s, 4); s += __shfl_xor(s, 8);
            if (r15 == 0) {
                int trow = wr*64 + mi*16 + rg*4 + reg;
                sred[trow][wc] = s;
            }
        }
    }
    __syncthreads();
    if (tid < BM)
        spart[(size_t)nblk * Mtot + m0 + tid] = sred[tid][0] + sred[tid][1];
#undef STAGE_A
#undef STAGE_B
#undef LDA
#undef LDB
}

// ---------------- Kernel 3: reduce 8 partials + softmax over L (per b) ----------------
__global__ __launch_bounds__(256) void softmax_kernel(
    const float* __restrict__ spart,   // [8][Mtot], m = l*32+b
    float* __restrict__ attn)          // [B][L]
{
    int b = blockIdx.x;
    int t = threadIdx.x;
    __shared__ float rmax[4], rsum[4];
    float sv[8];
    float mx = -1e30f;
    #pragma unroll
    for (int i = 0; i < 8; i++) {
        int l = t + i * 256;
        int m = l * Bdim + b;
        float s = 0.f;
        #pragma unroll
        for (int p = 0; p < 8; p++) s += spart[(size_t)p * Mtot + m];
        sv[i] = s;
        mx = fmaxf(mx, s);
    }
    #pragma unroll
    for (int off = 1; off < 64; off <<= 1) mx = fmaxf(mx, __shfl_xor(mx, off));
    if ((t & 63) == 0) rmax[t >> 6] = mx;
    __syncthreads();
    mx = fmaxf(fmaxf(rmax[0], rmax[1]), fmaxf(rmax[2], rmax[3]));
    float sum = 0.f;
    #pragma unroll
    for (int i = 0; i < 8; i++) { sv[i] = __expf(sv[i] - mx); sum += sv[i]; }
    #pragma unroll
    for (int off = 1; off < 64; off <<= 1) sum += __shfl_xor(sum, off);
    if ((t & 63) == 0) rsum[t >> 6] = sum;
    __syncthreads();
    sum = rsum[0] + rsum[1] + rsum[2] + rsum[3];
    float inv = 1.f / sum;
    #pragma unroll
    for (int i = 0; i < 8; i++)
        attn[(size_t)b * Ldim + t + i * 256] = sv[i] * inv;
}

// ---------------- Kernel 4: context partials over L-chunks (f32 enc, L3-warm) ----------------
__global__ __launch_bounds__(256) void context_part_kernel(
    const float* __restrict__ enc,     // [L*B][H] f32
    const float* __restrict__ attn,    // [B][L]
    float* __restrict__ cpart)         // [64][B][H]
{
    int b = blockIdx.x & 31;
    int c = blockIdx.x >> 5;
    int t = threadIdx.x;
    float4 acc = {0.f, 0.f, 0.f, 0.f};
    int l0 = c * 32;
    for (int i = 0; i < 32; i++) {
        int l = l0 + i;
        float a = attn[(size_t)b * Ldim + l];
        float4 e = *(const float4*)(enc + (size_t)(l * Bdim + b) * Hdim + t * 4);
        acc.x += a * e.x; acc.y += a * e.y; acc.z += a * e.z; acc.w += a * e.w;
    }
    *(float4*)(cpart + ((size_t)c * Bdim + b) * Hdim + t * 4) = acc;
}

// ---------------- Kernel 5: reduce context partials ----------------
__global__ __launch_bounds__(256) void context_reduce_kernel(
    const float* __restrict__ cpart, float* __restrict__ out)
{
    int idx = blockIdx.x * 256 + threadIdx.x;
    float s = 0.f;
    for (int c = 0; c < 64; c++) s += cpart[(size_t)c * (Bdim * Hdim) + idx];
    out[idx] = s;
}

extern "C" void kernel_launch(void* const* d_in, const int* in_sizes, int n_in,
                              void* d_out, int out_size, void* d_ws, size_t ws_size,
                              hipStream_t stream)
{
    const float* hidden = (const float*)d_in[0];
    const float* enc    = (const float*)d_in[1];   // (L,B,H), m = l*32+b
    const float* attn_w = (const float*)d_in[2];
    const float* attn_b = (const float*)d_in[3];
    const float* vvec   = (const float*)d_in[4];
    float* out = (float*)d_out;

    char* ws = (char*)d_ws;
    size_t off = 0;
    short* w_bf   = (short*)(ws + off); off += (size_t)Hdim * Hdim * 2;       // 2.1 MB
    float* qbuf   = (float*)(ws + off); off += (size_t)Bdim * Hdim * 4;       // 0.13 MB
    float* spart  = (float*)(ws + off); off += (size_t)8 * Mtot * 4;          // 2.1 MB
    float* attnp  = (float*)(ws + off); off += (size_t)Mtot * 4;              // 0.26 MB
    float* cpart  = (float*)(ws + off);                                       // 8.4 MB

    convert_w_kernel<<<512, 256, 0, stream>>>(attn_w, w_bf);
    qproj_kernel<<<8192, 256, 0, stream>>>(hidden, attn_w, attn_b, qbuf);
    scores_kernel<<<4096, 256, 0, stream>>>(enc, w_bf, qbuf, vvec, spart);
    softmax_kernel<<<Bdim, 256, 0, stream>>>(spart, attnp);
    context_part_kernel<<<2048, 256, 0, stream>>>(enc, attnp, cpart);
    context_reduce_kernel<<<128, 256, 0, stream>>>(cpart, out);
}

// Round 14
// 296.452 us; speedup vs baseline: 1.1395x; 1.1156x over previous
//
#include <hip/hip_runtime.h>
#include <hip/hip_bf16.h>
#include <math.h>

#define Hdim 1024
#define Bdim 32
#define Ldim 2048
#define Mtot (Bdim*Ldim)   // 65536

typedef __attribute__((ext_vector_type(8))) short short8v;
typedef __attribute__((ext_vector_type(4))) short short4v;
typedef __attribute__((ext_vector_type(4))) float floatx4;

static __device__ inline short f2bf(float f) {
    union { float f; unsigned u; } x; x.f = f;
    unsigned r = x.u + 0x7FFF + ((x.u >> 16) & 1);   // RNE
    return (short)(r >> 16);
}
static __device__ inline short f2bf_hw(float f) {
    __hip_bfloat16 h = __float2bfloat16(f);
    return *reinterpret_cast<short*>(&h);
}

static __device__ inline float fast_tanh(float x) {
    float t = 2.0f * x;
    t = fminf(fmaxf(t, -30.0f), 30.0f);
    float e = __expf(t);
    return (e - 1.0f) / (e + 1.0f);
}

typedef __attribute__((address_space(1))) const void GVT;
typedef __attribute__((address_space(3))) void LVT;
static __device__ inline void gload_lds16(const void* g, void* l) {
    __builtin_amdgcn_global_load_lds((GVT*)g, (LVT*)l, 16, 0, 0);
}

// ---------------- Kernel 0: W_e (= attn_w[:, H:]) f32 -> compact bf16 [1024][1024] ----------------
__global__ __launch_bounds__(256) void convert_w_kernel(
    const float* __restrict__ attn_w, short* __restrict__ w_bf)
{
    int t = blockIdx.x * 256 + threadIdx.x;
    int o = t >> 7;
    int c = t & 127;
    const float* src = attn_w + (size_t)o * 2 * Hdim + Hdim + c * 8;
    float4 a = *(const float4*)(src);
    float4 b = *(const float4*)(src + 4);
    short8v v;
    v[0]=f2bf(a.x); v[1]=f2bf(a.y); v[2]=f2bf(a.z); v[3]=f2bf(a.w);
    v[4]=f2bf(b.x); v[5]=f2bf(b.y); v[6]=f2bf(b.z); v[7]=f2bf(b.w);
    *(short8v*)(w_bf + (size_t)o * Hdim + c * 8) = v;
}

// ---------------- Kernel 1: q[b][o] = hidden[b]·W_h[o] + bias[o] ----------------
__global__ __launch_bounds__(256) void qproj_kernel(
    const float* __restrict__ hidden, const float* __restrict__ attn_w,
    const float* __restrict__ attn_b, float* __restrict__ qbuf)
{
    int w = blockIdx.x * 4 + (threadIdx.x >> 6);
    int lane = threadIdx.x & 63;
    int o = w >> 5;
    int b = w & 31;
    const float* hrow = hidden + b * Hdim;
    const float* wrow = attn_w + (size_t)o * 2 * Hdim;
    float s = 0.f;
    #pragma unroll
    for (int i = 0; i < 16; i++) s += hrow[lane + i*64] * wrow[lane + i*64];
    s += __shfl_xor(s, 1);  s += __shfl_xor(s, 2);  s += __shfl_xor(s, 4);
    s += __shfl_xor(s, 8);  s += __shfl_xor(s, 16); s += __shfl_xor(s, 32);
    if (lane == 0) qbuf[b * Hdim + o] = s + attn_b[o];
}

// ---------------- Kernel 2: fused-A GEMM, 2-deep A-reg pipeline, 3 blocks/CU ----
// r12 structure; launch_bounds(256,3) gives ~170-reg budget so the 2 A-reg sets
// (+32 VGPR) fit beside the 64-AGPR accumulator WITHOUT scratch spill (r12's bug).
// A: f32 global -> regs (2 iters ahead) -> cvt -> swizzled ds_write (1 iter ahead).
// B: bf16 gload_lds, pre-swizzled source (0 conflicts). vmcnt counted; raw barrier.
#define BM 128
#define BN 128
#define BK 32
#define NKT 32

__global__ __launch_bounds__(256, 3) void scores_kernel(
    const float* __restrict__ enc,      // [Mtot][1024] f32 (L,B,H) m=l*32+b
    const short* __restrict__ w_bf,     // [1024][1024] bf16
    const float* __restrict__ qbuf,     // [B][H]
    const float* __restrict__ vvec,     // [H]
    float* __restrict__ spart)          // [8][Mtot]
{
    __shared__ short As[2][BM * BK];    // 2 x 8 KB
    __shared__ short Bs[2][BN * BK];    // 2 x 8 KB
    __shared__ float sred[BM][2];

    // XCD swizzle: 8 nblk sharers of one A-panel on one XCD. grid 4096 = 8*8*64.
    int hw = blockIdx.x;
    int xcd = hw & 7;
    int i5  = hw >> 3;
    int nblk  = i5 & 7;
    int mtile = xcd * 64 + (i5 >> 3);
    int m0 = mtile * BM;
    int n0 = nblk * BN;

    int tid  = threadIdx.x;
    int w    = tid >> 6;
    int l    = tid & 63;
    int wr = w >> 1, wc = w & 1;
    int r15 = l & 15;
    int kc  = l >> 4;
    int rg  = l >> 4;

    // ---- A staging lane constants: slots cover rows arow, arow+64; chunk acol ----
    int arow = tid >> 2;                // 0..63
    int acol = tid & 3;
    int asw  = (tid >> 3) & 3;          // s(row) = (row>>1)&3 (same for both slots)
    const float* agp = enc + (size_t)(m0 + arow) * Hdim + acol * 8;
    const int awoff0 = arow * BK + ((acol ^ asw) * 8);
    const int awoff1 = (arow + 64) * BK + ((acol ^ asw) * 8);

    // ---- B gload staging: pre-swizzled source ----
    const short* bgp = w_bf + (size_t)(n0 + w*32 + (l >> 2)) * Hdim
                            + (((l & 3) ^ ((l >> 3) & 3)) * 8);
#define STAGE_B(bb, k0) do { \
    gload_lds16(bgp + (k0),                      &Bs[bb][(w*32)      * BK]); \
    gload_lds16(bgp + (k0) + 16*(size_t)Hdim,    &Bs[bb][(w*32 + 16) * BK]); \
} while (0)

    // ---- swizzled fragment reads ----
    int q = (r15 >> 1) & 3;
    int rc = (kc ^ q) * 8;
#define LDA(mi) (*(const short8v*)(&As[cur][(wr*64 + (mi)*16 + r15) * BK + rc]))
#define LDB(ni) (*(const short8v*)(&Bs[cur][(wc*64 + (ni)*16 + r15) * BK + rc]))

    floatx4 acc[4][4];
    #pragma unroll
    for (int i = 0; i < 4; i++)
        #pragma unroll
        for (int j = 0; j < 4; j++) acc[i][j] = (floatx4){0.f, 0.f, 0.f, 0.f};

    // two A-reg sets: tile t lives in set t&1
    float4 A0_[4], A1_[4];

#define LOAD_SET0(k0) do { \
    A0_[0] = *(const float4*)(agp + (k0)); \
    A0_[1] = *(const float4*)(agp + (k0) + 4); \
    A0_[2] = *(const float4*)(agp + (k0) + 64*(size_t)Hdim); \
    A0_[3] = *(const float4*)(agp + (k0) + 64*(size_t)Hdim + 4); \
} while (0)
#define LOAD_SET1(k0) do { \
    A1_[0] = *(const float4*)(agp + (k0)); \
    A1_[1] = *(const float4*)(agp + (k0) + 4); \
    A1_[2] = *(const float4*)(agp + (k0) + 64*(size_t)Hdim); \
    A1_[3] = *(const float4*)(agp + (k0) + 64*(size_t)Hdim + 4); \
} while (0)
#define CVT_WRITE(SET, bb) do { \
    short8v s0, s1; \
    s0[0]=f2bf_hw(SET[0].x); s0[1]=f2bf_hw(SET[0].y); s0[2]=f2bf_hw(SET[0].z); s0[3]=f2bf_hw(SET[0].w); \
    s0[4]=f2bf_hw(SET[1].x); s0[5]=f2bf_hw(SET[1].y); s0[6]=f2bf_hw(SET[1].z); s0[7]=f2bf_hw(SET[1].w); \
    s1[0]=f2bf_hw(SET[2].x); s1[1]=f2bf_hw(SET[2].y); s1[2]=f2bf_hw(SET[2].z); s1[3]=f2bf_hw(SET[2].w); \
    s1[4]=f2bf_hw(SET[3].x); s1[5]=f2bf_hw(SET[3].y); s1[6]=f2bf_hw(SET[3].z); s1[7]=f2bf_hw(SET[3].w); \
    *(short8v*)(&As[bb][awoff0]) = s0; \
    *(short8v*)(&As[bb][awoff1]) = s1; \
} while (0)

    // prologue: tile0 -> buf0 (set0), tile1 loads in flight (set1)
    STAGE_B(0, 0);
    LOAD_SET0(0);
    LOAD_SET1(BK);
    CVT_WRITE(A0_, 0);
    __syncthreads();    // one-time full drain

    #pragma unroll 2
    for (int kt = 0; kt < NKT; kt++) {
        int cur = kt & 1;
        int nxt = cur ^ 1;
        bool haveB = (kt + 1 < NKT);
        bool haveA = (kt + 2 < NKT);

        // issue order matters: B first, then A (FIFO -> vmcnt(4) drains B only)
        if (haveB) STAGE_B(nxt, (kt + 1) * BK);
        if (haveA) { if (kt & 1) LOAD_SET1((kt + 2) * BK); else LOAD_SET0((kt + 2) * BK); }

        short8v af[4], bf[4];
        #pragma unroll
        for (int mi = 0; mi < 4; mi++) af[mi] = LDA(mi);
        #pragma unroll
        for (int ni = 0; ni < 4; ni++) bf[ni] = LDB(ni);
        #pragma unroll
        for (int mi = 0; mi < 4; mi++)
            #pragma unroll
            for (int ni = 0; ni < 4; ni++)
                acc[mi][ni] = __builtin_amdgcn_mfma_f32_16x16x32_bf16(af[mi], bf[ni], acc[mi][ni], 0, 0, 0);

        // write tile kt+1's A (loads issued a full iteration ago -> covered)
        if (haveB) { if ((kt + 1) & 1) CVT_WRITE(A1_, nxt); else CVT_WRITE(A0_, nxt); }

        if (haveB) {
            if (haveA) asm volatile("s_waitcnt vmcnt(4)" ::: "memory");  // B(t+1) done, A(t+2) flying
            else       asm volatile("s_waitcnt vmcnt(0)" ::: "memory");
            asm volatile("s_waitcnt lgkmcnt(0)" ::: "memory");           // ds_writes visible
            __builtin_amdgcn_s_barrier();
        }
    }

    // ---- epilogue: tanh(proj + q) * v, reduce over this block's 128 cols ----
    #pragma unroll
    for (int mi = 0; mi < 4; mi++) {
        float rs[4] = {0.f, 0.f, 0.f, 0.f};
        #pragma unroll
        for (int ni = 0; ni < 4; ni++) {
            int o = n0 + wc*64 + ni*16 + r15;
            float vo = vvec[o];
            #pragma unroll
            for (int reg = 0; reg < 4; reg++) {
                int trow = wr*64 + mi*16 + rg*4 + reg;
                int b = trow & 31;
                float p = acc[mi][ni][reg] + qbuf[b * Hdim + o];
                rs[reg] += fast_tanh(p) * vo;
            }
        }
        #pragma unroll
        for (int reg = 0; reg < 4; reg++) {
            float s = rs[reg];
            s += __shfl_xor(s, 1); s += __shfl_xor(s, 2);
            s += __shfl_xor(s, 4); s += __shfl_xor(s, 8);
            if (r15 == 0) {
                int trow = wr*64 + mi*16 + rg*4 + reg;
                sred[trow][wc] = s;
            }
        }
    }
    __syncthreads();
    if (tid < BM)
        spart[(size_t)nblk * Mtot + m0 + tid] = sred[tid][0] + sred[tid][1];
#undef STAGE_B
#undef LDA
#undef LDB
#undef LOAD_SET0
#undef LOAD_SET1
#undef CVT_WRITE
}

// ---------------- Kernel 3: reduce 8 partials + softmax over L (per b) ----------------
__global__ __launch_bounds__(256) void softmax_kernel(
    const float* __restrict__ spart,   // [8][Mtot], m = l*32+b
    float* __restrict__ attn)          // [B][L]
{
    int b = blockIdx.x;
    int t = threadIdx.x;
    __shared__ float rmax[4], rsum[4];
    float sv[8];
    float mx = -1e30f;
    #pragma unroll
    for (int i = 0; i < 8; i++) {
        int l = t + i * 256;
        int m = l * Bdim + b;
        float s = 0.f;
        #pragma unroll
        for (int p = 0; p < 8; p++) s += spart[(size_t)p * Mtot + m];
        sv[i] = s;
        mx = fmaxf(mx, s);
    }
    #pragma unroll
    for (int off = 1; off < 64; off <<= 1) mx = fmaxf(mx, __shfl_xor(mx, off));
    if ((t & 63) == 0) rmax[t >> 6] = mx;
    __syncthreads();
    mx = fmaxf(fmaxf(rmax[0], rmax[1]), fmaxf(rmax[2], rmax[3]));
    float sum = 0.f;
    #pragma unroll
    for (int i = 0; i < 8; i++) { sv[i] = __expf(sv[i] - mx); sum += sv[i]; }
    #pragma unroll
    for (int off = 1; off < 64; off <<= 1) sum += __shfl_xor(sum, off);
    if ((t & 63) == 0) rsum[t >> 6] = sum;
    __syncthreads();
    sum = rsum[0] + rsum[1] + rsum[2] + rsum[3];
    float inv = 1.f / sum;
    #pragma unroll
    for (int i = 0; i < 8; i++)
        attn[(size_t)b * Ldim + t + i * 256] = sv[i] * inv;
}

// ---------------- Kernel 4: context partials over L-chunks (f32 enc, L3-warm) ----------------
__global__ __launch_bounds__(256) void context_part_kernel(
    const float* __restrict__ enc,     // [L*B][H] f32
    const float* __restrict__ attn,    // [B][L]
    float* __restrict__ cpart)         // [64][B][H]
{
    int b = blockIdx.x & 31;
    int c = blockIdx.x >> 5;
    int t = threadIdx.x;
    float4 acc = {0.f, 0.f, 0.f, 0.f};
    int l0 = c * 32;
    for (int i = 0; i < 32; i++) {
        int l = l0 + i;
        float a = attn[(size_t)b * Ldim + l];
        float4 e = *(const float4*)(enc + (size_t)(l * Bdim + b) * Hdim + t * 4);
        acc.x += a * e.x; acc.y += a * e.y; acc.z += a * e.z; acc.w += a * e.w;
    }
    *(float4*)(cpart + ((size_t)c * Bdim + b) * Hdim + t * 4) = acc;
}

// ---------------- Kernel 5: reduce context partials ----------------
__global__ __launch_bounds__(256) void context_reduce_kernel(
    const float* __restrict__ cpart, float* __restrict__ out)
{
    int idx = blockIdx.x * 256 + threadIdx.x;
    float s = 0.f;
    for (int c = 0; c < 64; c++) s += cpart[(size_t)c * (Bdim * Hdim) + idx];
    out[idx] = s;
}

extern "C" void kernel_launch(void* const* d_in, const int* in_sizes, int n_in,
                              void* d_out, int out_size, void* d_ws, size_t ws_size,
                              hipStream_t stream)
{
    const float* hidden = (const float*)d_in[0];
    const float* enc    = (const float*)d_in[1];   // (L,B,H), m = l*32+b
    const float* attn_w = (const float*)d_in[2];
    const float* attn_b = (const float*)d_in[3];
    const float* vvec   = (const float*)d_in[4];
    float* out = (float*)d_out;

    char* ws = (char*)d_ws;
    size_t off = 0;
    short* w_bf   = (short*)(ws + off); off += (size_t)Hdim * Hdim * 2;       // 2.1 MB
    float* qbuf   = (float*)(ws + off); off += (size_t)Bdim * Hdim * 4;       // 0.13 MB
    float* spart  = (float*)(ws + off); off += (size_t)8 * Mtot * 4;          // 2.1 MB
    float* attnp  = (float*)(ws + off); off += (size_t)Mtot * 4;              // 0.26 MB
    float* cpart  = (float*)(ws + off);                                       // 8.4 MB

    convert_w_kernel<<<512, 256, 0, stream>>>(attn_w, w_bf);
    qproj_kernel<<<8192, 256, 0, stream>>>(hidden, attn_w, attn_b, qbuf);
    scores_kernel<<<4096, 256, 0, stream>>>(enc, w_bf, qbuf, vvec, spart);
    softmax_kernel<<<Bdim, 256, 0, stream>>>(spart, attnp);
    context_part_kernel<<<2048, 256, 0, stream>>>(enc, attnp, cpart);
    context_reduce_kernel<<<128, 256, 0, stream>>>(cpart, out);
}